// Round 4
// baseline (176.885 us; speedup 1.0000x reference)
//
#include <hip/hip_runtime.h>

// Problem constants (from reference):
constexpr int kB    = 32;
constexpr int kTin  = 512;
constexpr int kTout = 2048;
constexpr int kA    = 384;   // ADIM
constexpr int kC4   = kA / 4; // 96 float4 per output row

constexpr int kBlocksPerBatch = 16;
constexpr int kRowsPerBlock   = kTout / kBlocksPerBatch; // 128

// Native clang vector (HIP float4 is a class; nontemporal builtin rejects it).
typedef float v4f __attribute__((ext_vector_type(4)));

// ---------------------------------------------------------------------------
// Single fused kernel: per-block redundant duration-cumsum (LDS scan) +
// searchsorted + gather + pitch/energy pointwise embed + bias.
//
// Grid: 32 batches x 16 blocks = 512 blocks, 384 threads (6 waves).
// Each thread owns channel-quad c4 = tid % 96 -> weights live in ~24 VGPRs
// for the whole row loop. 4 rows in flight per iteration (sub = tid / 96).
// Non-temporal stores keep the 100 MB out-stream from evicting hs in L2.
//
// NOTE: binary search must be the guarded while-loop. 512 entries => 513
// outcomes => up to 10 iterations; a fixed 9-iter unroll leaves interval
// width 1 (wrong idx), and an unguarded 10-iter unroll can read cum[512]
// out of bounds. (R2/R3 post-mortem.)
// ---------------------------------------------------------------------------
__global__ __launch_bounds__(384) void va_fused_kernel(
    const float* __restrict__ hs,         // [B, T_IN, ADIM]
    const int*   __restrict__ durations,  // [B, T_IN]
    const int*   __restrict__ input_lengths, // [B]
    const v4f*   __restrict__ pitch_t,    // [B*T_OUT] (PDIM=4 packed)
    const float* __restrict__ energy_t,   // [B*T_OUT] (EDIM=1)
    const v4f*   __restrict__ pitch_w,    // [ADIM] rows of 4
    const float* __restrict__ pitch_b,    // [ADIM]
    const float* __restrict__ energy_w,   // [ADIM]
    const float* __restrict__ energy_b,   // [ADIM]
    v4f*         __restrict__ out)        // [B*T_OUT*kC4]
{
    __shared__ int bufA[kTin];
    __shared__ int bufB[kTin];

    const int tid = threadIdx.x;
    const int b   = blockIdx.x >> 4;       // batch
    const int blk = blockIdx.x & 15;       // slice within batch
    const int len = input_lengths[b];

    // ---- Phase 1: masked-duration inclusive scan (Hillis-Steele, ping-pong)
    for (int i = tid; i < kTin; i += 384)
        bufA[i] = (i < len) ? durations[b * kTin + i] : 0;
    __syncthreads();
    int* scur = bufA;
    int* snxt = bufB;
    for (int off = 1; off < kTin; off <<= 1) {
        for (int i = tid; i < kTin; i += 384) {
            int v = scur[i];
            if (i >= off) v += scur[i - off];
            snxt[i] = v;
        }
        __syncthreads();
        int* t = scur; scur = snxt; snxt = t;
    }
    int total = scur[kTin - 1];
    if (total == 0) {
        // Reference refills masked durations with ones if sum == 0 (rare;
        // block-uniform branch).
        __syncthreads();
        for (int i = tid; i < kTin; i += 384)
            scur[i] = (i < len) ? 1 : 0;
        __syncthreads();
        for (int off = 1; off < kTin; off <<= 1) {
            for (int i = tid; i < kTin; i += 384) {
                int v = scur[i];
                if (i >= off) v += scur[i - off];
                snxt[i] = v;
            }
            __syncthreads();
            int* t = scur; scur = snxt; snxt = t;
        }
        total = scur[kTin - 1];
    }
    const int* __restrict__ cum = scur;

    // ---- Phase 2: gather + embed. Register-resident weights per channel quad.
    const int c4  = tid % kC4;   // fixed channel quad
    const int sub = tid / kC4;   // 0..3 row slot
    const int a0  = c4 * 4;

    const v4f w0 = pitch_w[a0];
    const v4f w1 = pitch_w[a0 + 1];
    const v4f w2 = pitch_w[a0 + 2];
    const v4f w3 = pitch_w[a0 + 3];
    v4f ew;
    ew.x = energy_w[a0];     ew.y = energy_w[a0 + 1];
    ew.z = energy_w[a0 + 2]; ew.w = energy_w[a0 + 3];
    v4f bias;
    bias.x = pitch_b[a0]     + energy_b[a0];
    bias.y = pitch_b[a0 + 1] + energy_b[a0 + 1];
    bias.z = pitch_b[a0 + 2] + energy_b[a0 + 2];
    bias.w = pitch_b[a0 + 3] + energy_b[a0 + 3];

    const int row0 = blk * kRowsPerBlock;
    const int hs_base = b * kTin * kA;     // < 2^23, 32-bit safe
    const int row_base = b * kTout;        // batch row offset

    for (int r = sub; r < kRowsPerBlock; r += 4) {
        const int to  = row0 + r;
        const int row = row_base + to;     // < 65536

        v4f h = (v4f)(0.f);
        if (to < total) {
            // searchsorted(cum, to, 'right'): first index with cum[idx] > to.
            // MUST be the guarded loop (up to 10 iters) — see header comment.
            int lo = 0, hi = kTin;
            while (lo < hi) {
                const int mid = (lo + hi) >> 1;
                if (cum[mid] <= to) lo = mid + 1; else hi = mid;
            }
            const int sidx = (lo < kTin) ? lo : (kTin - 1);
            h = *(const v4f*)(hs + hs_base + sidx * kA + a0);
        }
        const v4f  pt = pitch_t[row];
        const float e = energy_t[row];
        v4f o;
        o.x = h.x + pt.x * w0.x + pt.y * w0.y + pt.z * w0.z + pt.w * w0.w + e * ew.x + bias.x;
        o.y = h.y + pt.x * w1.x + pt.y * w1.y + pt.z * w1.z + pt.w * w1.w + e * ew.y + bias.y;
        o.z = h.z + pt.x * w2.x + pt.y * w2.y + pt.z * w2.z + pt.w * w2.w + e * ew.z + bias.z;
        o.w = h.w + pt.x * w3.x + pt.y * w3.y + pt.z * w3.z + pt.w * w3.w + e * ew.w + bias.w;
        __builtin_nontemporal_store(o, &out[row * kC4 + c4]);
    }
}

extern "C" void kernel_launch(void* const* d_in, const int* in_sizes, int n_in,
                              void* d_out, int out_size, void* d_ws, size_t ws_size,
                              hipStream_t stream) {
    // setup_inputs() order:
    // 0 hs[32,512,384] f32 | 1 durations[32,512] int | 2 input_lengths[32] int
    // 3 pitch_target[32,2048,4] f32 | 4 energy_target[32,2048,1] f32
    // 5 duration_mask (unused) | 6 variance_mask (unused)
    // 7 pitch_w[384,4] f32 | 8 pitch_b[384] f32 | 9 energy_w[384,1] f32 | 10 energy_b[384] f32
    const float* hs            = (const float*)d_in[0];
    const int*   durations     = (const int*)d_in[1];
    const int*   input_lengths = (const int*)d_in[2];
    const float* pitch_t       = (const float*)d_in[3];
    const float* energy_t      = (const float*)d_in[4];
    const float* pitch_w       = (const float*)d_in[7];
    const float* pitch_b       = (const float*)d_in[8];
    const float* energy_w      = (const float*)d_in[9];
    const float* energy_b      = (const float*)d_in[10];
    float* out = (float*)d_out;

    va_fused_kernel<<<kB * kBlocksPerBatch, 384, 0, stream>>>(
        hs, durations, input_lengths,
        (const v4f*)pitch_t, energy_t,
        (const v4f*)pitch_w, pitch_b, energy_w, energy_b,
        (v4f*)out);
}